// Round 1
// baseline (17066.000 us; speedup 1.0000x reference)
//
#include <hip/hip_runtime.h>
#include <hip/hip_bf16.h>

// Sizes (fixed by the problem)
#define T_STEPS 512
#define B_SZ    64
#define A_SZ    128
#define H_SZ    512
#define KTOT    640          // 128 (x) + 512 (h) unified K dimension
#define KPAD    652          // padded row stride in floats (163 float4 slots)
#define KP4     163
#define NWG     256
#define WG_THR  512

#define WEFF_SZ (4194304u)   // 64*128*512 floats
#define HBUF_SZ (65536u)     // 2 * 64*512 floats
#define LDSB    (48*KPAD*4 + 64)   // 16 weight rows + 32 act rows + bias = 125,248 B

// ---------------------------------------------------------------------------
// Kernel 1: W_eff[b] = w_out + w_out @ M[b]   (out: [64][128][512] fp32 in ws)
// grid 2048 = 64 b * 4 a-tiles(32) * 8 j-tiles(64), block 256
// ---------------------------------------------------------------------------
__global__ __launch_bounds__(256) void weff_kernel(
    const float* __restrict__ M, const float* __restrict__ w_out,
    float* __restrict__ weff)
{
    __shared__ float wl[32*36];   // [a_local 32][i 32] pad 36
    __shared__ float ml[32*68];   // [i 32][j_local 64] pad 68
    const int blk = blockIdx.x;
    const int b   = blk >> 5;
    const int at  = (blk >> 3) & 3;
    const int jt  = blk & 7;
    const int tid = threadIdx.x;
    const int ap  = tid >> 4;     // 0..15 (a-pair)
    const int jq  = tid & 15;     // 0..15 (j-quad)
    float4 acc0 = {0.f,0.f,0.f,0.f};
    float4 acc1 = {0.f,0.f,0.f,0.f};

    for (int ik = 0; ik < 16; ++ik){
        {   // stage w_out tile [32a][32i]
            const int a = tid >> 3, i4 = tid & 7;
            const float4 v = *(const float4*)&w_out[(at*32 + a)*512 + ik*32 + i4*4];
            *(float4*)&wl[a*36 + i4*4] = v;
        }
        {   // stage M tile [32i][64j]
            const int i = tid >> 3, j8 = tid & 7;
            const float* src = &M[((size_t)b*512 + (size_t)(ik*32 + i))*512 + jt*64 + j8*8];
            const float4 v0 = *(const float4*)(src);
            const float4 v1 = *(const float4*)(src + 4);
            *(float4*)&ml[i*68 + j8*8]     = v0;
            *(float4*)&ml[i*68 + j8*8 + 4] = v1;
        }
        __syncthreads();
        #pragma unroll
        for (int i0 = 0; i0 < 32; i0 += 4){
            const float4 w0 = *(const float4*)&wl[(ap*2+0)*36 + i0];
            const float4 w1 = *(const float4*)&wl[(ap*2+1)*36 + i0];
            #pragma unroll
            for (int di = 0; di < 4; ++di){
                const float4 mv = *(const float4*)&ml[(i0+di)*68 + jq*4];
                const float wa = (di==0)?w0.x:(di==1)?w0.y:(di==2)?w0.z:w0.w;
                const float wb = (di==0)?w1.x:(di==1)?w1.y:(di==2)?w1.z:w1.w;
                acc0.x = fmaf(wa, mv.x, acc0.x); acc0.y = fmaf(wa, mv.y, acc0.y);
                acc0.z = fmaf(wa, mv.z, acc0.z); acc0.w = fmaf(wa, mv.w, acc0.w);
                acc1.x = fmaf(wb, mv.x, acc1.x); acc1.y = fmaf(wb, mv.y, acc1.y);
                acc1.z = fmaf(wb, mv.z, acc1.z); acc1.w = fmaf(wb, mv.w, acc1.w);
            }
        }
        __syncthreads();
    }
    const int ag = at*32 + ap*2;
    const int jg = jt*64 + jq*4;
    {
        const float4 id0 = *(const float4*)&w_out[(ag+0)*512 + jg];
        const float4 id1 = *(const float4*)&w_out[(ag+1)*512 + jg];
        float4 o0, o1;
        o0.x = acc0.x + id0.x; o0.y = acc0.y + id0.y; o0.z = acc0.z + id0.z; o0.w = acc0.w + id0.w;
        o1.x = acc1.x + id1.x; o1.y = acc1.y + id1.y; o1.z = acc1.z + id1.z; o1.w = acc1.w + id1.w;
        *(float4*)&weff[((size_t)b*128 + (ag+0))*512 + jg] = o0;
        *(float4*)&weff[((size_t)b*128 + (ag+1))*512 + jg] = o1;
    }
}

// ---------------------------------------------------------------------------
// Grid-wide sense/generation barrier (agent-scope atomics in ws)
// ---------------------------------------------------------------------------
__device__ __forceinline__ void grid_sync(unsigned* cnt, unsigned* gen, unsigned target)
{
    __syncthreads();
    if (threadIdx.x == 0){
        __threadfence();   // release h writes (agent scope: L2 writeback)
        const unsigned prev = __hip_atomic_fetch_add(cnt, 1u, __ATOMIC_ACQ_REL,
                                                     __HIP_MEMORY_SCOPE_AGENT);
        if (prev == (unsigned)(NWG - 1)){
            __hip_atomic_store(cnt, 0u, __ATOMIC_RELAXED, __HIP_MEMORY_SCOPE_AGENT);
            __hip_atomic_fetch_add(gen, 1u, __ATOMIC_RELEASE, __HIP_MEMORY_SCOPE_AGENT);
        } else {
            while (__hip_atomic_load(gen, __ATOMIC_ACQUIRE, __HIP_MEMORY_SCOPE_AGENT) < target){
                __builtin_amdgcn_s_sleep(4);
            }
        }
    }
    __syncthreads();
}

// ---------------------------------------------------------------------------
// Kernel 2: persistent cooperative recurrent kernel.
// 256 WGs x 512 thr. WG (gb,gr): samples b0..b0+31, hidden j0..j0+3 (all 4
// gates => local c/h update, ONE grid sync per step), out column a = gr.
// Weights in LDS (once), W_eff slice + c state in registers, act = [x_t | h]
// staged in LDS per step.
// ---------------------------------------------------------------------------
__global__ __launch_bounds__(WG_THR) void rnn_kernel(
    const float* __restrict__ x,    const float* __restrict__ w_ih,
    const float* __restrict__ w_hh, const float* __restrict__ b_ih,
    const float* __restrict__ b_hh, const float* __restrict__ h0,
    const float* __restrict__ c0,   const float* __restrict__ b_out,
    const float* __restrict__ weff, float* __restrict__ hbuf,
    unsigned* __restrict__ bar,     float* __restrict__ out)
{
    extern __shared__ float lds[];
    float* w_s    = lds;               // [16][KPAD]  rows r = jl*4+g
    float* act_s  = lds + 16*KPAD;     // [32][KPAD]  [0:128)=x_t, [128:640)=h
    float* bias_s = lds + 48*KPAD;     // [16]

    const int tid = threadIdx.x;
    const int wg  = blockIdx.x;
    const int gb  = wg >> 7;           // 0..1  (sample group of 32)
    const int gr  = wg & 127;          // 0..127 (j-slice / out column)
    const int b0  = gb * 32;
    const int j0  = gr * 4;

    // ---- one-time: weights -> LDS ----
    {
        const int r = tid >> 5, q = tid & 31;      // 16 rows x 32 threads
        const int g = r & 3, jl = r >> 2;
        const int grow = g*512 + j0 + jl;
        #pragma unroll
        for (int m = 0; m < 5; ++m){
            const int s = q*5 + m;                 // float4 slot 0..159
            float4 v;
            if (s < 32) v = *(const float4*)&w_ih[grow*128 + s*4];
            else        v = *(const float4*)&w_hh[grow*512 + (s-32)*4];
            *(float4*)&w_s[r*KPAD + s*4] = v;
        }
    }
    if (tid < 16){
        const int g = tid & 3, jl = tid >> 2;
        const int grow = g*512 + j0 + jl;
        bias_s[tid] = b_ih[grow] + b_hh[grow];
    }

    // ---- persistent registers ----
    const int obl = tid >> 4;          // 0..31  out-proj/staging: sample
    const int okc = tid & 15;          // 0..15  out-proj/staging: k-chunk
    float wef[32];
    {
        const float* wsrc = &weff[((size_t)(b0 + obl)*128 + gr)*512 + okc*32];
        #pragma unroll
        for (int i = 0; i < 32; ++i) wef[i] = wsrc[i];
    }
    const float bo = b_out[gr];

    const int ks = tid & 15;           // gates: k-split lane
    const int bg = (tid >> 4) & 7;     // gates: sample group of 4
    const int rg = tid >> 7;           // 0..3: j-local (owns all 4 gates of j0+rg)
    float cst[4];
    #pragma unroll
    for (int bb = 0; bb < 4; ++bb)
        cst[bb] = c0[(size_t)(b0 + bg*4 + bb)*512 + j0 + rg];

    const float4* w_s4  = (const float4*)w_s;
    const float4* act4c = (const float4*)act_s;
    float4*       act4  = (float4*)act_s;

    for (int t = 0; t < T_STEPS; ++t){
        // ---- stage act = [x_t | h_prev] ----
        {
            const float* hsrc = (t == 0) ? h0 : (hbuf + (((t & 1) ^ 1) << 15));
            const float4* xrow = (const float4*)&x[((size_t)(b0 + obl)*T_STEPS + t)*A_SZ];
            const float4* hrow = (const float4*)&hsrc[(size_t)(b0 + obl)*H_SZ];
            float4 vv[10];
            #pragma unroll
            for (int m = 0; m < 10; ++m){
                const int s = okc*10 + m;
                vv[m] = (s < 32) ? xrow[s] : hrow[s - 32];
            }
            #pragma unroll
            for (int m = 0; m < 10; ++m)
                act4[obl*KP4 + okc*10 + m] = vv[m];
        }
        __syncthreads();

        // ---- output projection for step t-1 (uses staged h) ----
        if (t > 0){
            float p = 0.f;
            #pragma unroll
            for (int i8 = 0; i8 < 8; ++i8){
                const float4 av = act4c[obl*KP4 + 32 + okc*8 + i8];
                p = fmaf(wef[i8*4+0], av.x, p);
                p = fmaf(wef[i8*4+1], av.y, p);
                p = fmaf(wef[i8*4+2], av.z, p);
                p = fmaf(wef[i8*4+3], av.w, p);
            }
            p += __shfl_xor(p, 1); p += __shfl_xor(p, 2);
            p += __shfl_xor(p, 4); p += __shfl_xor(p, 8);
            if (okc == 0)
                out[((size_t)(b0 + obl)*T_STEPS + (t-1))*A_SZ + gr] = p + bo;
        }

        // ---- gates: 16 rows x 32 samples, K=640, 4x4 reg blocking, k-split 16 ----
        float acc[4][4];
        #pragma unroll
        for (int rr = 0; rr < 4; ++rr)
            #pragma unroll
            for (int bb = 0; bb < 4; ++bb) acc[rr][bb] = 0.f;

        #pragma unroll
        for (int m = 0; m < 10; ++m){
            const int slot = ks + 16*m;            // strided slots: bank-friendly
            float4 wv[4], av[4];
            #pragma unroll
            for (int rr = 0; rr < 4; ++rr) wv[rr] = w_s4[(rg*4+rr)*KP4 + slot];
            #pragma unroll
            for (int bb = 0; bb < 4; ++bb) av[bb] = act4c[(bg*4+bb)*KP4 + slot];
            #pragma unroll
            for (int rr = 0; rr < 4; ++rr)
                #pragma unroll
                for (int bb = 0; bb < 4; ++bb){
                    acc[rr][bb] = fmaf(wv[rr].x, av[bb].x, acc[rr][bb]);
                    acc[rr][bb] = fmaf(wv[rr].y, av[bb].y, acc[rr][bb]);
                    acc[rr][bb] = fmaf(wv[rr].z, av[bb].z, acc[rr][bb]);
                    acc[rr][bb] = fmaf(wv[rr].w, av[bb].w, acc[rr][bb]);
                }
        }
        #pragma unroll
        for (int rr = 0; rr < 4; ++rr)
            #pragma unroll
            for (int bb = 0; bb < 4; ++bb){
                float v = acc[rr][bb];
                v += __shfl_xor(v, 1); v += __shfl_xor(v, 2);
                v += __shfl_xor(v, 4); v += __shfl_xor(v, 8);
                acc[rr][bb] = v;
            }

        // ---- LSTM cell update: lane ks==0 owns (j = j0+rg, b = b0+bg*4+bb) ----
        if (ks == 0){
            float* hw = hbuf + ((t & 1) << 15);
            #pragma unroll
            for (int bb = 0; bb < 4; ++bb){
                const float gi = acc[0][bb] + bias_s[rg*4 + 0];
                const float gf = acc[1][bb] + bias_s[rg*4 + 1];
                const float gg = acc[2][bb] + bias_s[rg*4 + 2];
                const float go = acc[3][bb] + bias_s[rg*4 + 3];
                const float si = 1.f / (1.f + __expf(-gi));
                const float sf = 1.f / (1.f + __expf(-gf));
                const float tg = tanhf(gg);
                const float so = 1.f / (1.f + __expf(-go));
                const float c  = sf * cst[bb] + si * tg;
                cst[bb] = c;
                const float h  = so * tanhf(c);
                hw[(size_t)(b0 + bg*4 + bb)*H_SZ + j0 + rg] = h;
            }
        }
        grid_sync(bar, bar + 1, (unsigned)(t + 1));
    }

    // ---- epilogue: out[T-1] from final h (buffer (T-1)&1 == 1) ----
    {
        const float4* hrow = (const float4*)&hbuf[(((T_STEPS-1) & 1) << 15)
                                                  + (size_t)(b0 + obl)*H_SZ];
        #pragma unroll
        for (int m = 0; m < 10; ++m){
            const int s = okc*10 + m;
            if (s >= 32) act4[obl*KP4 + s] = hrow[s - 32];
        }
    }
    __syncthreads();
    {
        float p = 0.f;
        #pragma unroll
        for (int i8 = 0; i8 < 8; ++i8){
            const float4 av = act4c[obl*KP4 + 32 + okc*8 + i8];
            p = fmaf(wef[i8*4+0], av.x, p);
            p = fmaf(wef[i8*4+1], av.y, p);
            p = fmaf(wef[i8*4+2], av.z, p);
            p = fmaf(wef[i8*4+3], av.w, p);
        }
        p += __shfl_xor(p, 1); p += __shfl_xor(p, 2);
        p += __shfl_xor(p, 4); p += __shfl_xor(p, 8);
        if (okc == 0)
            out[((size_t)(b0 + obl)*T_STEPS + (T_STEPS-1))*A_SZ + gr] = p + bo;
    }
}

// ---------------------------------------------------------------------------
extern "C" void kernel_launch(void* const* d_in, const int* in_sizes, int n_in,
                              void* d_out, int out_size, void* d_ws, size_t ws_size,
                              hipStream_t stream)
{
    const float* x     = (const float*)d_in[0];
    const float* w_ih  = (const float*)d_in[1];
    const float* w_hh  = (const float*)d_in[2];
    const float* b_ih  = (const float*)d_in[3];
    const float* b_hh  = (const float*)d_in[4];
    const float* M     = (const float*)d_in[5];
    const float* w_out = (const float*)d_in[6];
    const float* b_out = (const float*)d_in[7];
    const float* h0    = (const float*)d_in[8];
    const float* c0    = (const float*)d_in[9];
    float* out = (float*)d_out;

    const size_t need = (size_t)(WEFF_SZ + HBUF_SZ)*4 + 8;
    if (ws_size < need) return;   // visible failure instead of corruption

    float*    ws   = (float*)d_ws;
    float*    weff = ws;
    float*    hbuf = ws + WEFF_SZ;
    unsigned* bar  = (unsigned*)(ws + WEFF_SZ + HBUF_SZ);

    hipMemsetAsync((void*)bar, 0, 2*sizeof(unsigned), stream);

    hipLaunchKernelGGL(weff_kernel, dim3(2048), dim3(256), 0, stream, M, w_out, weff);

    hipFuncSetAttribute((const void*)rnn_kernel,
                        hipFuncAttributeMaxDynamicSharedMemorySize, LDSB);

    void* args[] = {
        (void*)&x, (void*)&w_ih, (void*)&w_hh, (void*)&b_ih, (void*)&b_hh,
        (void*)&h0, (void*)&c0, (void*)&b_out, (void*)&weff, (void*)&hbuf,
        (void*)&bar, (void*)&out
    };
    hipLaunchCooperativeKernel((const void*)rnn_kernel, dim3(NWG), dim3(WG_THR),
                               args, (unsigned)LDSB, stream);
}

// Round 2
// 12895.886 us; speedup vs baseline: 1.3234x; 1.3234x over previous
//
#include <hip/hip_runtime.h>
#include <hip/hip_bf16.h>

// Sizes (fixed by the problem)
#define T_STEPS 512
#define B_SZ    64
#define A_SZ    128
#define H_SZ    512
#define NWG     256
#define THR     512

#define WEFF_SZ 4194304u     // 64*128*512 floats
#define HBUF_SZ 65536u       // 8 XCD * 2 parity * 8 samples * 512 floats
#define BAR_U32 512u         // 8 XCD * 64 u32 (256B apart): cnt, gen, slotctr

// LDS layout (floats): wlds f4[64][128] | act f4[8][160] | bias[64]
#define W_F4    8192
#define ACT_F4  1280
#define LDSB    (4*(W_F4 + ACT_F4)*4 + 256)   // 131072 + 20480 + 256 = 151808

// ---------------------------------------------------------------------------
// Kernel 1: W_eff[b] = w_out + w_out @ M[b]   (out: [64][128][512] fp32 in ws)
// ---------------------------------------------------------------------------
__global__ __launch_bounds__(256) void weff_kernel(
    const float* __restrict__ M, const float* __restrict__ w_out,
    float* __restrict__ weff)
{
    __shared__ float wl[32*36];
    __shared__ float ml[32*68];
    const int blk = blockIdx.x;
    const int b   = blk >> 5;
    const int at  = (blk >> 3) & 3;
    const int jt  = blk & 7;
    const int tid = threadIdx.x;
    const int ap  = tid >> 4;
    const int jq  = tid & 15;
    float4 acc0 = {0.f,0.f,0.f,0.f};
    float4 acc1 = {0.f,0.f,0.f,0.f};

    for (int ik = 0; ik < 16; ++ik){
        {
            const int a = tid >> 3, i4 = tid & 7;
            const float4 v = *(const float4*)&w_out[(at*32 + a)*512 + ik*32 + i4*4];
            *(float4*)&wl[a*36 + i4*4] = v;
        }
        {
            const int i = tid >> 3, j8 = tid & 7;
            const float* src = &M[((size_t)b*512 + (size_t)(ik*32 + i))*512 + jt*64 + j8*8];
            const float4 v0 = *(const float4*)(src);
            const float4 v1 = *(const float4*)(src + 4);
            *(float4*)&ml[i*68 + j8*8]     = v0;
            *(float4*)&ml[i*68 + j8*8 + 4] = v1;
        }
        __syncthreads();
        #pragma unroll
        for (int i0 = 0; i0 < 32; i0 += 4){
            const float4 w0 = *(const float4*)&wl[(ap*2+0)*36 + i0];
            const float4 w1 = *(const float4*)&wl[(ap*2+1)*36 + i0];
            #pragma unroll
            for (int di = 0; di < 4; ++di){
                const float4 mv = *(const float4*)&ml[(i0+di)*68 + jq*4];
                const float wa = (di==0)?w0.x:(di==1)?w0.y:(di==2)?w0.z:w0.w;
                const float wb = (di==0)?w1.x:(di==1)?w1.y:(di==2)?w1.z:w1.w;
                acc0.x = fmaf(wa, mv.x, acc0.x); acc0.y = fmaf(wa, mv.y, acc0.y);
                acc0.z = fmaf(wa, mv.z, acc0.z); acc0.w = fmaf(wa, mv.w, acc0.w);
                acc1.x = fmaf(wb, mv.x, acc1.x); acc1.y = fmaf(wb, mv.y, acc1.y);
                acc1.z = fmaf(wb, mv.z, acc1.z); acc1.w = fmaf(wb, mv.w, acc1.w);
            }
        }
        __syncthreads();
    }
    const int ag = at*32 + ap*2;
    const int jg = jt*64 + jq*4;
    {
        const float4 id0 = *(const float4*)&w_out[(ag+0)*512 + jg];
        const float4 id1 = *(const float4*)&w_out[(ag+1)*512 + jg];
        float4 o0, o1;
        o0.x = acc0.x + id0.x; o0.y = acc0.y + id0.y; o0.z = acc0.z + id0.z; o0.w = acc0.w + id0.w;
        o1.x = acc1.x + id1.x; o1.y = acc1.y + id1.y; o1.z = acc1.z + id1.z; o1.w = acc1.w + id1.w;
        *(float4*)&weff[((size_t)b*128 + (ag+0))*512 + jg] = o0;
        *(float4*)&weff[((size_t)b*128 + (ag+1))*512 + jg] = o1;
    }
}

// ---------------------------------------------------------------------------
// Kernel 2: persistent cooperative recurrent kernel, XCD-local.
// 256 WGs x 512 thr, 1 WG/CU (LDS-forced) => exactly 32 WGs per XCD.
// XCD x owns samples b0=x*8..x*8+7; its 32 CUs hold full w_hh in LDS once.
// h round-trips through the XCD's own (coherent) L2: relaxed atomics only,
// NO agent fences / L2 flushes. One 32-WG XCD-local barrier per step.
// ---------------------------------------------------------------------------
__global__ __launch_bounds__(THR) void rnn_kernel(
    const float* __restrict__ x,    const float* __restrict__ w_ih,
    const float* __restrict__ w_hh, const float* __restrict__ b_ih,
    const float* __restrict__ b_hh, const float* __restrict__ h0,
    const float* __restrict__ c0,   const float* __restrict__ b_out,
    const float* __restrict__ weff, float* __restrict__ hbuf,
    unsigned* __restrict__ barws,   float* __restrict__ out)
{
    extern __shared__ float lds[];
    float4* wlds4  = (float4*)lds;                 // [64 rows][128 f4], XOR-swz
    float4* act4   = ((float4*)lds) + W_F4;        // [8 samples][160 f4], XOR-swz
    float*  bias_s = lds + 4*(W_F4 + ACT_F4);      // [64]
    __shared__ unsigned role_s;

    const int tid = threadIdx.x;

    // ---- discover XCD, claim a slot on it (relaxed agent atomic, init only) ----
    if (tid == 0){
        unsigned xcc;
        asm volatile("s_getreg_b32 %0, hwreg(20, 0, 32)" : "=s"(xcc));  // HW_REG_XCC_ID
        xcc &= 7u;
        const unsigned slot = __hip_atomic_fetch_add(&barws[xcc*64 + 2], 1u,
                                  __ATOMIC_RELAXED, __HIP_MEMORY_SCOPE_AGENT);
        role_s = (xcc << 5) | (slot & 31u);
    }
    __syncthreads();
    const int myx = (int)(role_s >> 5);
    const int s   = (int)(role_s & 31u);
    const int b0  = myx * 8;         // 8 samples of this XCD
    const int j0  = s * 16;          // 16 hidden units of this CU

    unsigned* cnt = &barws[myx*64 + 0];
    unsigned* gen = &barws[myx*64 + 1];
    float* hbX = hbuf + myx * 8192;  // [parity][8][512]

    // ---- one-time: w_hh rows (r = jl*4 + gate) -> LDS, XOR-swizzled ----
    {
        const int r = tid >> 3, p = tid & 7;
        const int g = r & 3, jlr = r >> 2;
        const float4* src = (const float4*)&w_hh[(size_t)(g*H_SZ + j0 + jlr)*H_SZ];
        const int e = r & 7;
        #pragma unroll
        for (int m = 0; m < 16; ++m){
            const int sl = p*16 + m;
            wlds4[r*128 + (sl ^ e)] = src[sl];
        }
    }
    if (tid < 64){
        const int g = tid & 3, jlr = tid >> 2;
        const int grow = g*H_SZ + j0 + jlr;
        bias_s[tid] = b_ih[grow] + b_hh[grow];
    }

    // ---- thread roles ----
    const int jl  = tid >> 5;        // 0..15 gates: hidden-local
    const int ks  = tid & 31;        // 0..31 gates: K-split lane
    const int sb  = tid >> 6;        // 0..7  stage/out-proj: sample
    const int l   = tid & 63;        // stage lane
    const int c_l = (tid >> 4) & 3;  // out-proj: column-local
    const int k_l = tid & 15;        // out-proj: K-split lane
    const int col = s*4 + c_l;
    const int eb  = sb & 7;          // act-row swizzle (== sb)

    // ---- persistent registers ----
    float4 wihv[4];                  // w_ih slice (loop-invariant!)
    #pragma unroll
    for (int g = 0; g < 4; ++g)
        wihv[g] = *(const float4*)&w_ih[(size_t)(g*H_SZ + j0 + jl)*A_SZ + ks*4];

    float4 wef4[8];                  // W_eff strided K-chunks
    #pragma unroll
    for (int i8 = 0; i8 < 8; ++i8)
        wef4[i8] = *(const float4*)&weff[((size_t)(b0 + sb)*A_SZ + col)*H_SZ + (k_l + 16*i8)*4];
    const float bo = b_out[col];

    float cst[8];                    // cell state (used by ks==0 lanes)
    #pragma unroll
    for (int bb = 0; bb < 8; ++bb)
        cst[bb] = c0[(size_t)(b0 + bb)*H_SZ + j0 + jl];

    for (int t = 0; t <= T_STEPS; ++t){
        // ---- stage act = [x_t | h_prev] (h via sc0 L1-bypass loads) ----
        {
            const float* hprev = hbX + (((t+1)&1) ? 4096 : 0) + sb*H_SZ;
            const float4* h0r  = (const float4*)&h0[(size_t)(b0+sb)*H_SZ];
            const float4* xr   = (const float4*)&x[((size_t)(b0+sb)*T_STEPS + (t < T_STEPS ? t : 0))*A_SZ];
            auto stage_one = [&](int sl){
                float4 v;
                if (sl < 32){
                    if (t < T_STEPS){ v = xr[sl]; act4[sb*160 + (sl ^ eb)] = v; }
                } else if (t == 0){
                    v = h0r[sl - 32];
                    act4[sb*160 + (sl ^ eb)] = v;
                } else {
                    float* hp = (float*)(hprev + (sl - 32)*4);
                    v.x = __hip_atomic_load(hp+0, __ATOMIC_RELAXED, __HIP_MEMORY_SCOPE_AGENT);
                    v.y = __hip_atomic_load(hp+1, __ATOMIC_RELAXED, __HIP_MEMORY_SCOPE_AGENT);
                    v.z = __hip_atomic_load(hp+2, __ATOMIC_RELAXED, __HIP_MEMORY_SCOPE_AGENT);
                    v.w = __hip_atomic_load(hp+3, __ATOMIC_RELAXED, __HIP_MEMORY_SCOPE_AGENT);
                    act4[sb*160 + (sl ^ eb)] = v;
                }
            };
            stage_one(2*l);
            stage_one(2*l + 1);
            if (l < 32) stage_one(128 + l);
        }
        __syncthreads();

        // ---- out-proj for step t-1 (reads staged h; lanes read consecutive slots) ----
        if (t > 0){
            float p = 0.f;
            #pragma unroll
            for (int i8 = 0; i8 < 8; ++i8){
                const float4 av = act4[sb*160 + ((32 + k_l + 16*i8) ^ eb)];
                p = fmaf(wef4[i8].x, av.x, p);
                p = fmaf(wef4[i8].y, av.y, p);
                p = fmaf(wef4[i8].z, av.z, p);
                p = fmaf(wef4[i8].w, av.w, p);
            }
            p += __shfl_xor(p, 1); p += __shfl_xor(p, 2);
            p += __shfl_xor(p, 4); p += __shfl_xor(p, 8);
            if (k_l == 0)
                out[((size_t)(b0 + sb)*T_STEPS + (t-1))*A_SZ + col] = p + bo;
        }
        if (t == T_STEPS) break;

        // ---- gates: 64 rows x 8 samples, K-split 32, acc[4 gates][8 samples] ----
        float acc[4][8];
        #pragma unroll
        for (int g = 0; g < 4; ++g)
            #pragma unroll
            for (int bb = 0; bb < 8; ++bb) acc[g][bb] = 0.f;

        {   // x part: w_ih from registers, x from LDS act
            float4 av[8];
            #pragma unroll
            for (int bb = 0; bb < 8; ++bb) av[bb] = act4[bb*160 + (ks ^ (bb&7))];
            #pragma unroll
            for (int g = 0; g < 4; ++g){
                #pragma unroll
                for (int bb = 0; bb < 8; ++bb){
                    acc[g][bb] = fmaf(wihv[g].x, av[bb].x, acc[g][bb]);
                    acc[g][bb] = fmaf(wihv[g].y, av[bb].y, acc[g][bb]);
                    acc[g][bb] = fmaf(wihv[g].z, av[bb].z, acc[g][bb]);
                    acc[g][bb] = fmaf(wihv[g].w, av[bb].w, acc[g][bb]);
                }
            }
        }
        #pragma unroll
        for (int m = 0; m < 4; ++m){   // h part
            const int hs = ks + 32*m;
            float4 wv[4];
            #pragma unroll
            for (int g = 0; g < 4; ++g){
                const int r = jl*4 + g;
                wv[g] = wlds4[r*128 + (hs ^ (r&7))];
            }
            float4 av[8];
            #pragma unroll
            for (int bb = 0; bb < 8; ++bb) av[bb] = act4[bb*160 + ((32 + hs) ^ (bb&7))];
            #pragma unroll
            for (int g = 0; g < 4; ++g)
                #pragma unroll
                for (int bb = 0; bb < 8; ++bb){
                    acc[g][bb] = fmaf(wv[g].x, av[bb].x, acc[g][bb]);
                    acc[g][bb] = fmaf(wv[g].y, av[bb].y, acc[g][bb]);
                    acc[g][bb] = fmaf(wv[g].z, av[bb].z, acc[g][bb]);
                    acc[g][bb] = fmaf(wv[g].w, av[bb].w, acc[g][bb]);
                }
        }
        // ---- K-reduction across the 32 ks lanes ----
        #pragma unroll
        for (int g = 0; g < 4; ++g)
            #pragma unroll
            for (int bb = 0; bb < 8; ++bb){
                float v = acc[g][bb];
                v += __shfl_xor(v, 1);  v += __shfl_xor(v, 2);
                v += __shfl_xor(v, 4);  v += __shfl_xor(v, 8);
                v += __shfl_xor(v, 16);
                acc[g][bb] = v;
            }

        // ---- LSTM cell update: lane ks==0 owns (j0+jl, all 8 samples) ----
        if (ks == 0){
            float* hc = hbX + ((t&1) ? 4096 : 0);
            #pragma unroll
            for (int bb = 0; bb < 8; ++bb){
                const float gi = acc[0][bb] + bias_s[jl*4 + 0];
                const float gf = acc[1][bb] + bias_s[jl*4 + 1];
                const float gg = acc[2][bb] + bias_s[jl*4 + 2];
                const float go = acc[3][bb] + bias_s[jl*4 + 3];
                const float si = 1.f / (1.f + __expf(-gi));
                const float sf = 1.f / (1.f + __expf(-gf));
                const float tg = tanhf(gg);
                const float so = 1.f / (1.f + __expf(-go));
                const float c  = sf * cst[bb] + si * tg;
                cst[bb] = c;
                const float h  = so * tanhf(c);
                __hip_atomic_store(&hc[bb*H_SZ + j0 + jl], h,
                                   __ATOMIC_RELAXED, __HIP_MEMORY_SCOPE_AGENT);
            }
        }
        __syncthreads();   // drains each wave's vmcnt -> h stores are in this XCD's L2

        // ---- XCD-local barrier: monotonic counter, relaxed atomics, no fences ----
        if (tid == 0){
            __atomic_signal_fence(__ATOMIC_SEQ_CST);
            const unsigned prev = __hip_atomic_fetch_add(cnt, 1u,
                                      __ATOMIC_RELAXED, __HIP_MEMORY_SCOPE_AGENT);
            if (prev + 1u == 32u*(unsigned)(t+1)){
                __hip_atomic_store(gen, (unsigned)(t+1),
                                   __ATOMIC_RELAXED, __HIP_MEMORY_SCOPE_AGENT);
            } else {
                while (__hip_atomic_load(gen, __ATOMIC_RELAXED,
                                         __HIP_MEMORY_SCOPE_AGENT) < (unsigned)(t+1))
                    __builtin_amdgcn_s_sleep(2);
            }
            __atomic_signal_fence(__ATOMIC_SEQ_CST);
        }
        __syncthreads();
    }
}

// ---------------------------------------------------------------------------
extern "C" void kernel_launch(void* const* d_in, const int* in_sizes, int n_in,
                              void* d_out, int out_size, void* d_ws, size_t ws_size,
                              hipStream_t stream)
{
    (void)in_sizes; (void)n_in; (void)out_size;
    const float* x     = (const float*)d_in[0];
    const float* w_ih  = (const float*)d_in[1];
    const float* w_hh  = (const float*)d_in[2];
    const float* b_ih  = (const float*)d_in[3];
    const float* b_hh  = (const float*)d_in[4];
    const float* M     = (const float*)d_in[5];
    const float* w_out = (const float*)d_in[6];
    const float* b_out = (const float*)d_in[7];
    const float* h0    = (const float*)d_in[8];
    const float* c0    = (const float*)d_in[9];
    float* out = (float*)d_out;

    const size_t need = (size_t)(WEFF_SZ + HBUF_SZ)*4 + BAR_U32*4;
    if (ws_size < need) return;   // visible failure instead of corruption

    float*    ws    = (float*)d_ws;
    float*    weff  = ws;
    float*    hbuf  = ws + WEFF_SZ;
    unsigned* barws = (unsigned*)(ws + WEFF_SZ + HBUF_SZ);

    hipMemsetAsync((void*)barws, 0, BAR_U32*4, stream);

    hipLaunchKernelGGL(weff_kernel, dim3(2048), dim3(256), 0, stream, M, w_out, weff);

    hipFuncSetAttribute((const void*)rnn_kernel,
                        hipFuncAttributeMaxDynamicSharedMemorySize, LDSB);

    void* args[] = {
        (void*)&x, (void*)&w_ih, (void*)&w_hh, (void*)&b_ih, (void*)&b_hh,
        (void*)&h0, (void*)&c0, (void*)&b_out, (void*)&weff, (void*)&hbuf,
        (void*)&barws, (void*)&out
    };
    hipLaunchCooperativeKernel((const void*)rnn_kernel, dim3(NWG), dim3(THR),
                               args, (unsigned)LDSB, stream);
}

// Round 4
// 12078.315 us; speedup vs baseline: 1.4129x; 1.0677x over previous
//
#include <hip/hip_runtime.h>
#include <hip/hip_bf16.h>

// Sizes (fixed by the problem)
#define T_STEPS 512
#define B_SZ    64
#define A_SZ    128
#define H_SZ    512
#define NWG     256
#define THR     512

#define WEFF_SZ 4194304u     // 64*128*512 floats
#define HBUF_SZ 65536u       // 8 XCD * 2 parity * 8 samples * 512 floats
#define BAR_U32 2048u        // 8 XCD * 256 u32 (1KB region): [0]=slotctr, [32+4s]=flag[s]
#define LDSB    98304        // dummy-large: forces 1 WG/CU (2*96KB > 160KB); act uses 16KB

// ---------------------------------------------------------------------------
// Kernel 1: W_eff[b] = w_out + w_out @ M[b]   (out: [64][128][512] fp32 in ws)
// ---------------------------------------------------------------------------
__global__ __launch_bounds__(256) void weff_kernel(
    const float* __restrict__ M, const float* __restrict__ w_out,
    float* __restrict__ weff)
{
    __shared__ float wl[32*36];
    __shared__ float ml[32*68];
    const int blk = blockIdx.x;
    const int b   = blk >> 5;
    const int at  = (blk >> 3) & 3;
    const int jt  = blk & 7;
    const int tid = threadIdx.x;
    const int ap  = tid >> 4;
    const int jq  = tid & 15;
    float4 acc0 = {0.f,0.f,0.f,0.f};
    float4 acc1 = {0.f,0.f,0.f,0.f};

    for (int ik = 0; ik < 16; ++ik){
        {
            const int a = tid >> 3, i4 = tid & 7;
            const float4 v = *(const float4*)&w_out[(at*32 + a)*512 + ik*32 + i4*4];
            *(float4*)&wl[a*36 + i4*4] = v;
        }
        {
            const int i = tid >> 3, j8 = tid & 7;
            const float* src = &M[((size_t)b*512 + (size_t)(ik*32 + i))*512 + jt*64 + j8*8];
            const float4 v0 = *(const float4*)(src);
            const float4 v1 = *(const float4*)(src + 4);
            *(float4*)&ml[i*68 + j8*8]     = v0;
            *(float4*)&ml[i*68 + j8*8 + 4] = v1;
        }
        __syncthreads();
        #pragma unroll
        for (int i0 = 0; i0 < 32; i0 += 4){
            const float4 w0 = *(const float4*)&wl[(ap*2+0)*36 + i0];
            const float4 w1 = *(const float4*)&wl[(ap*2+1)*36 + i0];
            #pragma unroll
            for (int di = 0; di < 4; ++di){
                const float4 mv = *(const float4*)&ml[(i0+di)*68 + jq*4];
                const float wa = (di==0)?w0.x:(di==1)?w0.y:(di==2)?w0.z:w0.w;
                const float wb = (di==0)?w1.x:(di==1)?w1.y:(di==2)?w1.z:w1.w;
                acc0.x = fmaf(wa, mv.x, acc0.x); acc0.y = fmaf(wa, mv.y, acc0.y);
                acc0.z = fmaf(wa, mv.z, acc0.z); acc0.w = fmaf(wa, mv.w, acc0.w);
                acc1.x = fmaf(wb, mv.x, acc1.x); acc1.y = fmaf(wb, mv.y, acc1.y);
                acc1.z = fmaf(wb, mv.z, acc1.z); acc1.w = fmaf(wb, mv.w, acc1.w);
            }
        }
        __syncthreads();
    }
    const int ag = at*32 + ap*2;
    const int jg = jt*64 + jq*4;
    {
        const float4 id0 = *(const float4*)&w_out[(ag+0)*512 + jg];
        const float4 id1 = *(const float4*)&w_out[(ag+1)*512 + jg];
        float4 o0, o1;
        o0.x = acc0.x + id0.x; o0.y = acc0.y + id0.y; o0.z = acc0.z + id0.z; o0.w = acc0.w + id0.w;
        o1.x = acc1.x + id1.x; o1.y = acc1.y + id1.y; o1.z = acc1.z + id1.z; o1.w = acc1.w + id1.w;
        *(float4*)&weff[((size_t)b*128 + (ag+0))*512 + jg] = o0;
        *(float4*)&weff[((size_t)b*128 + (ag+1))*512 + jg] = o1;
    }
}

// ---- DPP helpers: lane-reduce without touching the LDS pipe -----------------
// Valid by construction: 0xB1 = quad_perm xor1, 0x4E = quad_perm xor2 (exact);
// 0x141 = row_half_mirror == xor4 AFTER bits0,1 reduced; 0x140 = row_mirror ==
// xor8 AFTER bits0..2 reduced. xor16 needs ds_swizzle (crosses row-of-16).
template<int CTRL>
__device__ __forceinline__ float dppadd(float v){
    const int o = __builtin_amdgcn_mov_dpp(__float_as_int(v), CTRL, 0xF, 0xF, true);
    return v + __int_as_float(o);
}
__device__ __forceinline__ float red16(float v){     // sum over ks bits 0..3
    v = dppadd<0xB1>(v); v = dppadd<0x4E>(v);
    v = dppadd<0x141>(v); v = dppadd<0x140>(v);
    return v;
}
__device__ __forceinline__ float red32(float v){     // sum over ks bits 0..4
    v = red16(v);
    v += __int_as_float(__builtin_amdgcn_ds_swizzle(__float_as_int(v), 0x401F));
    return v;
}
__device__ __forceinline__ float sigm(float x){ return 1.f / (1.f + __expf(-x)); }
__device__ __forceinline__ float tanh_fast(float x){
    const float xc = fminf(fmaxf(x, -9.f), 9.f);
    const float e  = __expf(2.f * xc);
    return (e - 1.f) * (1.f / (e + 1.f));
}

// ---------------------------------------------------------------------------
// Kernel 2: persistent cooperative recurrent kernel, XCD-local, flag-based.
// 256 WGs x 512 thr, 1 WG/CU (LDS-forced) => 32 WGs/XCD. XCD x owns samples
// x*8..x*8+7. h exchanged through the XCD's own L2: plain stores + vmcnt drain
// (inside __syncthreads) + per-WG flag store; consumers spin per-lane on the
// producer flag their slot needs, then sc0 (L1-bypass) vector loads.
// ---------------------------------------------------------------------------
__global__ __launch_bounds__(THR, 2) void rnn_kernel(
    const float* __restrict__ x,    const float* __restrict__ w_ih,
    const float* __restrict__ w_hh, const float* __restrict__ b_ih,
    const float* __restrict__ b_hh, const float* __restrict__ h0,
    const float* __restrict__ c0,   const float* __restrict__ b_out,
    const float* __restrict__ weff, float* __restrict__ hbuf,
    unsigned* __restrict__ barws,   float* __restrict__ out)
{
    extern __shared__ float lds[];
    float4* act = (float4*)lds;          // [8 samples][128 f4] = 16 KB of the 96K
    __shared__ unsigned role_s;

    const int tid = threadIdx.x;

    // ---- discover XCD, claim a slot (relaxed agent RMW, init only) ----
    if (tid == 0){
        unsigned xcc;
        asm volatile("s_getreg_b32 %0, hwreg(20, 0, 32)" : "=s"(xcc));  // HW_REG_XCC_ID
        xcc &= 7u;
        const unsigned slot = __hip_atomic_fetch_add(&barws[xcc*256 + 0], 1u,
                                  __ATOMIC_RELAXED, __HIP_MEMORY_SCOPE_AGENT);
        role_s = (xcc << 5) | (slot & 31u);
    }
    __syncthreads();
    const int myx = (int)(role_s >> 5);
    const int s   = (int)(role_s & 31u);
    const int b0  = myx * 8;             // this XCD's 8 samples
    const int j0  = s * 16;              // this CU's 16 hidden units

    unsigned* flg  = barws + myx*256 + 32;   // flag[s] at flg[4*s] (16B apart)
    float*    hbX  = hbuf + myx * 8192;      // [parity][8][512] floats

    // ---- thread roles ----
    const int jl  = tid >> 5;        // 0..15 gates: hidden-local (j = j0+jl)
    const int ks  = tid & 31;        // 0..31 gates: K-split lane
    const int sb  = tid >> 6;        // 0..7  stage/out-proj: sample (== wave)
    const int l   = tid & 63;        // stage lane
    const int c_l = (tid >> 4) & 3;  // out-proj: column-local
    const int k_l = tid & 15;        // out-proj: K-split lane
    const int col = s*4 + c_l;

    // ---- persistent registers ----
    float4 whh[4][4];                // w_hh slice: 4 gates x 4 K-chunks (f4)
    #pragma unroll
    for (int g = 0; g < 4; ++g)
        #pragma unroll
        for (int m = 0; m < 4; ++m)
            whh[g][m] = *(const float4*)&w_hh[(size_t)(g*H_SZ + j0 + jl)*H_SZ + (ks + 32*m)*4];
    float4 wihv[4];
    #pragma unroll
    for (int g = 0; g < 4; ++g)
        wihv[g] = *(const float4*)&w_ih[(size_t)(g*H_SZ + j0 + jl)*A_SZ + ks*4];
    float bg[4];
    #pragma unroll
    for (int g = 0; g < 4; ++g){
        const int grow = g*H_SZ + j0 + jl;
        bg[g] = b_ih[grow] + b_hh[grow];
    }
    float4 wef4[8];
    #pragma unroll
    for (int i8 = 0; i8 < 8; ++i8)
        wef4[i8] = *(const float4*)&weff[((size_t)(b0 + sb)*A_SZ + col)*H_SZ + (k_l + 16*i8)*4];
    const float bo = b_out[col];
    float cst = c0[(size_t)(b0 + (ks & 7))*H_SZ + j0 + jl];   // lane ks<8: sample ks

    // x(0) prefetch
    float4 xv[8];
    #pragma unroll
    for (int bb = 0; bb < 8; ++bb)
        xv[bb] = *(const float4*)&x[((size_t)(b0+bb)*T_STEPS + 0)*A_SZ + ks*4];

    for (int t = 0; t <= T_STEPS; ++t){
        // ---- (a) stage h(t-1) into act: spin producer flags, sc0 vector loads ----
        {
            const int bb = sb;
            if (t > 0){
                unsigned* f1 = flg + ((l >> 2)       ) * 4;
                unsigned* f2 = flg + (16 + (l >> 2)  ) * 4;
                while (__hip_atomic_load(f1, __ATOMIC_RELAXED, __HIP_MEMORY_SCOPE_AGENT)
                       < (unsigned)t) __builtin_amdgcn_s_sleep(1);
                while (__hip_atomic_load(f2, __ATOMIC_RELAXED, __HIP_MEMORY_SCOPE_AGENT)
                       < (unsigned)t) __builtin_amdgcn_s_sleep(1);
            }
            const float4* hb = (t == 0)
                ? ((const float4*)h0)  + (size_t)(b0 + bb)*128
                : ((const float4*)hbX) + (((t+1)&1) ? 1024 : 0) + bb*128;
            const float4* p1 = hb + l;
            const float4* p2 = hb + l + 64;
            float4 v1, v2;
            asm volatile("global_load_dwordx4 %0, %2, off sc0\n\t"
                         "global_load_dwordx4 %1, %3, off sc0\n\t"
                         "s_waitcnt vmcnt(0)"
                         : "=&v"(v1), "=&v"(v2) : "v"(p1), "v"(p2) : "memory");
            act[bb*128 + l]      = v1;
            act[bb*128 + l + 64] = v2;
        }
        __syncthreads();

        if (t < T_STEPS){
            // ---- (c) gates: acc[4 gates][8 samples], K-split 32 ----
            float acc[4][8];
            #pragma unroll
            for (int g = 0; g < 4; ++g)
                #pragma unroll
                for (int bb = 0; bb < 8; ++bb) acc[g][bb] = 0.f;

            #pragma unroll
            for (int bb = 0; bb < 8; ++bb){   // x part (registers)
                const float4 av = xv[bb];
                #pragma unroll
                for (int g = 0; g < 4; ++g){
                    acc[g][bb] = fmaf(wihv[g].x, av.x, acc[g][bb]);
                    acc[g][bb] = fmaf(wihv[g].y, av.y, acc[g][bb]);
                    acc[g][bb] = fmaf(wihv[g].z, av.z, acc[g][bb]);
                    acc[g][bb] = fmaf(wihv[g].w, av.w, acc[g][bb]);
                }
            }
            #pragma unroll
            for (int m = 0; m < 4; ++m){      // h part (act LDS + whh regs)
                float4 av[8];
                #pragma unroll
                for (int bb = 0; bb < 8; ++bb) av[bb] = act[bb*128 + ks + 32*m];
                #pragma unroll
                for (int g = 0; g < 4; ++g){
                    const float4 wv = whh[g][m];
                    #pragma unroll
                    for (int bb = 0; bb < 8; ++bb){
                        acc[g][bb] = fmaf(wv.x, av[bb].x, acc[g][bb]);
                        acc[g][bb] = fmaf(wv.y, av[bb].y, acc[g][bb]);
                        acc[g][bb] = fmaf(wv.z, av[bb].z, acc[g][bb]);
                        acc[g][bb] = fmaf(wv.w, av[bb].w, acc[g][bb]);
                    }
                }
            }
            // ---- reduce across 32 ks lanes (DPP + one swizzle) ----
            #pragma unroll
            for (int g = 0; g < 4; ++g)
                #pragma unroll
                for (int bb = 0; bb < 8; ++bb)
                    acc[g][bb] = red32(acc[g][bb]);

            // ---- static 8-way select: lane ks gets sample ks&7 ----
            float ga[4];
            const bool q0 = ks & 1, q1 = ks & 2, q2 = ks & 4;
            #pragma unroll
            for (int g = 0; g < 4; ++g){
                const float a01 = q0 ? acc[g][1] : acc[g][0];
                const float a23 = q0 ? acc[g][3] : acc[g][2];
                const float a45 = q0 ? acc[g][5] : acc[g][4];
                const float a67 = q0 ? acc[g][7] : acc[g][6];
                const float a03 = q1 ? a23 : a01;
                const float a47 = q1 ? a67 : a45;
                ga[g] = q2 ? a47 : a03;
            }
            // ---- (d) cell update: 8 lanes (sample = ks), plain h store ----
            if (ks < 8){
                const float gi = ga[0] + bg[0];
                const float gf = ga[1] + bg[1];
                const float gg = ga[2] + bg[2];
                const float go = ga[3] + bg[3];
                const float si = sigm(gi);
                const float sf = sigm(gf);
                const float tg = tanh_fast(gg);
                const float so = sigm(go);
                const float c  = sf * cst + si * tg;
                cst = c;
                const float h  = so * tanh_fast(c);
                float* hw = hbX + ((t&1) ? 4096 : 0);
                hw[(size_t)ks*H_SZ + j0 + jl] = h;
            }
        }

        // ---- (e) out-proj(t-1): uses act = h(t-1), DPP reduce over k_l ----
        if (t > 0){
            float p = 0.f;
            #pragma unroll
            for (int i8 = 0; i8 < 8; ++i8){
                const float4 av = act[sb*128 + k_l + 16*i8];
                p = fmaf(wef4[i8].x, av.x, p);
                p = fmaf(wef4[i8].y, av.y, p);
                p = fmaf(wef4[i8].z, av.z, p);
                p = fmaf(wef4[i8].w, av.w, p);
            }
            p = red16(p);
            if (k_l == 0)
                out[((size_t)(b0 + sb)*T_STEPS + (t-1))*A_SZ + col] = p + bo;
        }
        if (t == T_STEPS) break;

        // ---- (f) sync: drains every wave's vmcnt (h stores now in XCD L2),
        //      and closes all act reads before next iteration's stage writes ----
        __syncthreads();

        // ---- (g) publish: flag = t+1 (plain-ish relaxed store, own 16B slot) ----
        if (tid == 0)
            __hip_atomic_store(flg + s*4, (unsigned)(t+1),
                               __ATOMIC_RELAXED, __HIP_MEMORY_SCOPE_AGENT);

        // ---- (h) prefetch x(t+1) into registers (L1-cacheable plain loads) ----
        if (t + 1 < T_STEPS){
            #pragma unroll
            for (int bb = 0; bb < 8; ++bb)
                xv[bb] = *(const float4*)&x[((size_t)(b0+bb)*T_STEPS + (t+1))*A_SZ + ks*4];
        }
    }
}

// ---------------------------------------------------------------------------
extern "C" void kernel_launch(void* const* d_in, const int* in_sizes, int n_in,
                              void* d_out, int out_size, void* d_ws, size_t ws_size,
                              hipStream_t stream)
{
    (void)in_sizes; (void)n_in; (void)out_size;
    const float* x     = (const float*)d_in[0];
    const float* w_ih  = (const float*)d_in[1];
    const float* w_hh  = (const float*)d_in[2];
    const float* b_ih  = (const float*)d_in[3];
    const float* b_hh  = (const float*)d_in[4];
    const float* M     = (const float*)d_in[5];
    const float* w_out = (const float*)d_in[6];
    const float* b_out = (const float*)d_in[7];
    const float* h0    = (const float*)d_in[8];
    const float* c0    = (const float*)d_in[9];
    float* out = (float*)d_out;

    const size_t need = (size_t)(WEFF_SZ + HBUF_SZ)*4 + BAR_U32*4;
    if (ws_size < need) return;   // visible failure instead of corruption

    float*    ws    = (float*)d_ws;
    float*    weff  = ws;
    float*    hbuf  = ws + WEFF_SZ;
    unsigned* barws = (unsigned*)(ws + WEFF_SZ + HBUF_SZ);

    hipMemsetAsync((void*)barws, 0, BAR_U32*4, stream);

    hipLaunchKernelGGL(weff_kernel, dim3(2048), dim3(256), 0, stream, M, w_out, weff);

    hipFuncSetAttribute((const void*)rnn_kernel,
                        hipFuncAttributeMaxDynamicSharedMemorySize, LDSB);

    void* args[] = {
        (void*)&x, (void*)&w_ih, (void*)&w_hh, (void*)&b_ih, (void*)&b_hh,
        (void*)&h0, (void*)&c0, (void*)&b_out, (void*)&weff, (void*)&hbuf,
        (void*)&barws, (void*)&out
    };
    hipLaunchCooperativeKernel((const void*)rnn_kernel, dim3(NWG), dim3(THR),
                               args, (unsigned)LDSB, stream);
}